// Round 7
// baseline (267.236 us; speedup 1.0000x reference)
//
#include <hip/hip_runtime.h>
#include <math.h>

#define HH 512
#define WW 512
#define IMG (HH*WW)
#define NIMG_PER 96   // B*C = 32*3
#define NIMG 192      // pred + targ
#define NBIN 256      // max_r
#define EPSV 1e-8f

#define IMGC (257*512)         // float2 per image, layout [kx][y], kx=0..256
#define NTILE 33               // 8-column tiles
#define SLOT 580               // per-FFT LDS stride in float2; fsw(511)=574<580

// octal-digit reversal of 9-bit index (3 radix-8 stages)
__device__ __forceinline__ int drev(int s) {
    return ((s & 7) << 6) | (s & 56) | (s >> 6);
}
// bank swizzle on float2 element index
__device__ __forceinline__ int fsw(int a) { return a + (a >> 3); }

__device__ __forceinline__ float2 cmul(float2 a, float2 b) {
    return make_float2(a.x*b.x - a.y*b.y, a.x*b.y + a.y*b.x);
}
#define C_ADD(a,b) make_float2((a).x+(b).x, (a).y+(b).y)
#define C_SUB(a,b) make_float2((a).x-(b).x, (a).y-(b).y)
#define C_NI(a)    make_float2((a).y, -(a).x)   // * (-i)

// intra-wave "barrier": LDS is in-order per wave; just stop compiler reordering
__device__ __forceinline__ void wsync() {
    asm volatile("" ::: "memory");
    __builtin_amdgcn_wave_barrier();
    asm volatile("" ::: "memory");
}

// radix-8 DIF butterfly, negative exponent
__device__ __forceinline__ void bfly8(float2 x[8]) {
    const float R = 0.70710678118654752440f;
    float2 t0=C_ADD(x[0],x[4]), t4=C_SUB(x[0],x[4]);
    float2 t1=C_ADD(x[1],x[5]), t5=C_SUB(x[1],x[5]);
    float2 t2=C_ADD(x[2],x[6]), t6=C_SUB(x[2],x[6]);
    float2 t3=C_ADD(x[3],x[7]), t7=C_SUB(x[3],x[7]);
    float2 u0=C_ADD(t0,t2), u2=C_SUB(t0,t2);
    float2 u1=C_ADD(t1,t3), u3=C_SUB(t1,t3);
    x[0]=C_ADD(u0,u1); x[4]=C_SUB(u0,u1);
    { float2 n3 = C_NI(u3); x[2]=C_ADD(u2,n3); x[6]=C_SUB(u2,n3); }
    float2 s1 = make_float2(R*(t5.x + t5.y), R*(t5.y - t5.x));   // * (R - iR)
    float2 s2 = C_NI(t6);
    float2 s3 = make_float2(R*(t7.y - t7.x), -R*(t7.x + t7.y));  // * (-R - iR)
    float2 v0=C_ADD(t4,s2), v2=C_SUB(t4,s2);
    float2 v1=C_ADD(s1,s3), v3=C_SUB(s1,s3);
    x[1]=C_ADD(v0,v1); x[5]=C_SUB(v0,v1);
    { float2 n3 = C_NI(v3); x[3]=C_ADD(v2,n3); x[7]=C_SUB(v2,n3); }
}

// x[j] *= w^j, w = exp(i*ang); chain depth 3 for ILP
__device__ __forceinline__ void twiddle7(float2* x, float ang) {
    const float sn = __sinf(ang), cs = __cosf(ang);
    const float2 w1 = make_float2(cs, sn);
    const float2 w2 = cmul(w1, w1);
    const float2 w3 = cmul(w2, w1);
    const float2 w4 = cmul(w2, w2);
    const float2 w5 = cmul(w2, w3);
    const float2 w6 = cmul(w3, w3);
    const float2 w7 = cmul(w3, w4);
    x[1]=cmul(x[1],w1); x[2]=cmul(x[2],w2); x[3]=cmul(x[3],w3);
    x[4]=cmul(x[4],w4); x[5]=cmul(x[5],w5); x[6]=cmul(x[6],w6);
    x[7]=cmul(x[7],w7);
}

// ---------------------------------------------------------------------------
// Pass A: one block per 4 row-pairs (8 image rows). Pack rows (2s,2s+1) as
// a+ib, radix-8 512-pt DIF FFT, Hermitian unpack, LDS plane transpose, then
// write TRANSPOSED [kx][y]: each (kx, row-block) is one full 64B cacheline.
// ---------------------------------------------------------------------------
__global__ __launch_bounds__(256) void rowfft_kernel(
    const float* __restrict__ pred, const float* __restrict__ targ,
    float2* __restrict__ out, int img_base)
{
    __shared__ float2 sd[2320];        // 4*580 FFT slots; reused as 8*290 planes
    const int t = threadIdx.x;

    const int pb = blockIdx.x;         // rows pb*8 .. pb*8+7
    const int li = blockIdx.y;
    const int g  = img_base + li;
    const float* img = (g < NIMG_PER) ? (pred + (size_t)g * IMG)
                                      : (targ + (size_t)(g - NIMG_PER) * IMG);
    const float4* src4 = (const float4*)(img + (size_t)(pb*8) * WW);

    #pragma unroll
    for (int it = 0; it < 2; ++it) {
        const int id = it*256 + t;     // 0..511 = s*128 + x4
        const int s  = id >> 7;
        const int x4 = id & 127;
        const float4 va = src4[(2*s)   * 128 + x4];
        const float4 vb = src4[(2*s+1) * 128 + x4];
        float2* p = sd + s*SLOT + (4*x4 + (x4 >> 1));   // fsw(4*x4)
        p[0] = make_float2(va.x, vb.x);
        p[1] = make_float2(va.y, vb.y);
        p[2] = make_float2(va.z, vb.z);
        p[3] = make_float2(va.w, vb.w);
    }
    __syncthreads();

    const int i = t & 63;
    float2* p = sd + (t >> 6) * SLOT;
    float2 x[8];

    // stage 1: stride 64
    #pragma unroll
    for (int j = 0; j < 8; ++j) x[j] = p[fsw(i + 64*j)];
    bfly8(x);
    twiddle7(x, -0.012271846303085130f * (float)i);       // -2pi/512 * i
    #pragma unroll
    for (int j = 0; j < 8; ++j) p[fsw(i + 64*j)] = x[j];
    __syncthreads();

    // stage 2: groups of 64
    const int grp = i >> 3, i2 = i & 7;
    #pragma unroll
    for (int j = 0; j < 8; ++j) x[j] = p[fsw(64*grp + i2 + 8*j)];
    bfly8(x);
    twiddle7(x, -0.098174770424681038f * (float)i2);      // -2pi/64 * i2
    #pragma unroll
    for (int j = 0; j < 8; ++j) p[fsw(64*grp + i2 + 8*j)] = x[j];
    __syncthreads();

    // stage 3: contiguous 8
    #pragma unroll
    for (int j = 0; j < 8; ++j) x[j] = p[fsw(8*i + j)];
    bfly8(x);
    #pragma unroll
    for (int j = 0; j < 8; ++j) p[fsw(8*i + j)] = x[j];
    __syncthreads();

    // Hermitian unpack (lane->k mapping as R5/R6)
    const int w_ = t >> 6;
    const int k  = (w_ > 0) ? (((t & 7) << 6) | (t & 56) | w_)
                            : ((t < 32) ? (8*t + 4) : (8*(t - 32)));
    const int kk = (k <= 256) ? k : (512 - k);
    const int a1 = fsw(drev(kk));
    const int a2 = fsw(drev((512 - kk) & 511));
    const int a3 = fsw(drev(256));

    float2 A[4], Bv[4], Z[4];
    #pragma unroll
    for (int s = 0; s < 4; ++s) {
        const float2 P = sd[s*SLOT + a1];
        const float2 Q = sd[s*SLOT + a2];
        A[s]  = make_float2(0.5f*(P.x + Q.x), 0.5f*(P.y - Q.y));
        Bv[s] = make_float2(0.5f*(P.y + Q.y), 0.5f*(Q.x - P.x));
        Z[s]  = sd[s*SLOT + a3];
    }
    __syncthreads();

    // planes: plane r = 2s+h holds image row pb*8+r, stride 290
    {
        const int fb = fsw(kk);
        #pragma unroll
        for (int s = 0; s < 4; ++s) {
            sd[(2*s+0)*290 + fb] = A[s];
            sd[(2*s+1)*290 + fb] = Bv[s];
        }
    }
    if (t == 0) {
        const int fb = fsw(256);
        #pragma unroll
        for (int s = 0; s < 4; ++s) {
            sd[(2*s+0)*290 + fb] = make_float2(Z[s].x, 0.0f);
            sd[(2*s+1)*290 + fb] = make_float2(Z[s].y, 0.0f);
        }
    }
    __syncthreads();

    // transposed write: thread t -> column kx=t (t==0 also kx=256).
    // 8 rows = 64B = exactly one cacheline per kx -> L2 merges to full lines.
    {
        float2 p8[8];
        const int fc = fsw(t);
        #pragma unroll
        for (int r = 0; r < 8; ++r) p8[r] = sd[r*290 + fc];
        float4* d4 = (float4*)(out + (size_t)li * IMGC + (size_t)t * 512 + pb*8);
        #pragma unroll
        for (int q = 0; q < 4; ++q)
            d4[q] = make_float4(p8[2*q].x, p8[2*q].y, p8[2*q+1].x, p8[2*q+1].y);
        if (t == 0) {
            const int fc2 = fsw(256);
            #pragma unroll
            for (int r = 0; r < 8; ++r) p8[r] = sd[r*290 + fc2];
            float4* e4 = (float4*)(out + (size_t)li * IMGC + (size_t)256 * 512 + pb*8);
            #pragma unroll
            for (int q = 0; q < 4; ++q)
                e4[q] = make_float4(p8[2*q].x, p8[2*q].y, p8[2*q+1].x, p8[2*q+1].y);
        }
    }
}

// ---------------------------------------------------------------------------
// Pass B: one block per (image, 8-column tile); 4 waves, each WAVE-SYNCHRONOUS
// on its own 2 columns: coalesced global->reg stage 1, LDS exchanges with
// wave_barrier only, run-binning into per-wave replicas. One __syncthreads.
// ---------------------------------------------------------------------------
__global__ __launch_bounds__(256) void colfft_kernel(
    const float2* __restrict__ in, float* __restrict__ bins2, int img_base)
{
    __shared__ float2 sd[8*SLOT];
    __shared__ float  bs[8*257];      // wave w: replicas 2w, 2w+1
    const int t    = threadIdx.x;
    const int lane = t & 63;
    const int w    = t >> 6;

    // per-wave init of own replicas (no cross-wave dependency)
    for (int id = lane; id < 514; id += 64) bs[w*514 + id] = 0.0f;

    const int li    = blockIdx.y;
    const int x0    = blockIdx.x * 8;
    const int cbase = x0 + 2*w;
    const float2* src = in + (size_t)li * IMGC;

    const int i = lane;
    float2 x[2][8];

    // ---- stage 1: direct global->reg, fully coalesced (col-major cbuf)
    #pragma unroll
    for (int sl = 0; sl < 2; ++sl) {
        const int kx = cbase + sl;
        const float2* col = src + (size_t)(kx <= 256 ? kx : 256) * 512;
        #pragma unroll
        for (int j = 0; j < 8; ++j) x[sl][j] = col[i + 64*j];
        bfly8(x[sl]);
    }
    {
        const float ang = -0.012271846303085130f * (float)i;
        const float sn = __sinf(ang), cs = __cosf(ang);
        const float2 w1 = make_float2(cs, sn);
        const float2 w2 = cmul(w1,w1), w3 = cmul(w2,w1), w4 = cmul(w2,w2);
        const float2 w5 = cmul(w2,w3), w6 = cmul(w3,w3), w7 = cmul(w3,w4);
        #pragma unroll
        for (int sl = 0; sl < 2; ++sl) {
            x[sl][1]=cmul(x[sl][1],w1); x[sl][2]=cmul(x[sl][2],w2);
            x[sl][3]=cmul(x[sl][3],w3); x[sl][4]=cmul(x[sl][4],w4);
            x[sl][5]=cmul(x[sl][5],w5); x[sl][6]=cmul(x[sl][6],w6);
            x[sl][7]=cmul(x[sl][7],w7);
        }
    }
    {
        float2* p0 = sd + (2*w+0)*SLOT;
        float2* p1 = sd + (2*w+1)*SLOT;
        #pragma unroll
        for (int j = 0; j < 8; ++j) {
            const int a = fsw(i + 64*j);
            p0[a] = x[0][j]; p1[a] = x[1][j];
        }
    }
    wsync();

    // ---- stage 2
    const int grp = i >> 3, i2 = i & 7;
    #pragma unroll
    for (int sl = 0; sl < 2; ++sl) {
        float2* p = sd + (2*w+sl)*SLOT;
        #pragma unroll
        for (int j = 0; j < 8; ++j) x[sl][j] = p[fsw(64*grp + i2 + 8*j)];
        bfly8(x[sl]);
    }
    {
        const float ang = -0.098174770424681038f * (float)i2;
        const float sn = __sinf(ang), cs = __cosf(ang);
        const float2 w1 = make_float2(cs, sn);
        const float2 w2 = cmul(w1,w1), w3 = cmul(w2,w1), w4 = cmul(w2,w2);
        const float2 w5 = cmul(w2,w3), w6 = cmul(w3,w3), w7 = cmul(w3,w4);
        #pragma unroll
        for (int sl = 0; sl < 2; ++sl) {
            x[sl][1]=cmul(x[sl][1],w1); x[sl][2]=cmul(x[sl][2],w2);
            x[sl][3]=cmul(x[sl][3],w3); x[sl][4]=cmul(x[sl][4],w4);
            x[sl][5]=cmul(x[sl][5],w5); x[sl][6]=cmul(x[sl][6],w6);
            x[sl][7]=cmul(x[sl][7],w7);
        }
    }
    #pragma unroll
    for (int sl = 0; sl < 2; ++sl) {
        float2* p = sd + (2*w+sl)*SLOT;
        #pragma unroll
        for (int j = 0; j < 8; ++j) p[fsw(64*grp + i2 + 8*j)] = x[sl][j];
    }
    wsync();

    // ---- stage 3 + writeback (enables consecutive-ky regather)
    #pragma unroll
    for (int sl = 0; sl < 2; ++sl) {
        float2* p = sd + (2*w+sl)*SLOT;
        float2 y8[8];
        #pragma unroll
        for (int j = 0; j < 8; ++j) y8[j] = p[fsw(8*i + j)];
        bfly8(y8);
        #pragma unroll
        for (int j = 0; j < 8; ++j) p[fsw(8*i + j)] = y8[j];
    }
    wsync();

    // ---- binning: lane owns ky = 16h..16h+15 of column cl2; run-accumulate,
    // LDS atomic per bin change; adjacent h alternate replicas.
    {
        const int cl2 = lane & 1;
        const int h   = lane >> 1;           // 0..31
        const int kx  = cbase + cl2;
        const bool valid = (kx <= 256);
        const float scale = (kx == 0 || kx == 256) ? 0.5f : 1.0f;
        const int dxsq = (kx - 256) * (kx - 256);
        float* bsw = bs + w*514 + ((h & 1) ? 257 : 0);
        const float2* p = sd + (2*w+cl2)*SLOT;

        float acc = 0.0f;
        int prevb = 1000;
        #pragma unroll
        for (int j = 0; j < 16; ++j) {
            const int q = 64*(j & 7) + 8*((2*h + (j >> 3)) & 7) + (h >> 2); // drev(16h+j)
            const float2 v = p[fsw(q)];
            const float val = __logf(v.x*v.x + v.y*v.y + EPSV) * scale;
            const int dy = 16*h + j - 256;
            const int b  = (int)sqrtf((float)(dy*dy + dxsq));
            if (b != prevb) {
                if (prevb < NBIN && valid) atomicAdd(&bsw[prevb], acc);
                prevb = b; acc = val;
            } else {
                acc += val;
            }
        }
        if (prevb < NBIN && valid) atomicAdd(&bsw[prevb], acc);
    }
    __syncthreads();   // the ONE cross-wave barrier

    float v = 0.0f;
    #pragma unroll
    for (int r = 0; r < 8; ++r) v += bs[r*257 + t];
    bins2[((size_t)blockIdx.x * NIMG + (img_base + li)) * NBIN + t] = 2.0f * v;
}

// ---------------------------------------------------------------------------
// Reduce the 33 per-tile slices into bins[img][bin].
// ---------------------------------------------------------------------------
__global__ __launch_bounds__(256) void reduce_kernel(
    const float* __restrict__ bins2, float* __restrict__ bins)
{
    const int li = blockIdx.x;
    const int t  = threadIdx.x;
    float s = 0.0f;
    #pragma unroll
    for (int tile = 0; tile < NTILE; ++tile)
        s += bins2[((size_t)tile * NIMG + li) * NBIN + t];
    bins[(size_t)li * NBIN + t] = s;
}

// ---------------------------------------------------------------------------
__global__ __launch_bounds__(256) void counts_kernel(float* __restrict__ cnt)
{
    __shared__ float c[NBIN];
    const int t = threadIdx.x;
    c[t] = 0.0f;
    __syncthreads();

    const int base = blockIdx.x * 4096;
    #pragma unroll
    for (int i = 0; i < 16; ++i) {
        const int id = base + i * 256 + t;
        const int y = id >> 9, xx = id & 511;
        const int dy = y - 256, dx = xx - 256;
        const int b  = (int)sqrtf((float)(dy*dy + dx*dx));
        if (b < NBIN) atomicAdd(&c[b], 1.0f);
    }
    __syncthreads();
    if (c[t] != 0.0f) atomicAdd(&cnt[t], c[t]);
}

// ---------------------------------------------------------------------------
__global__ __launch_bounds__(256) void finalize_kernel(
    const float* __restrict__ bins, const float* __restrict__ cnt,
    float* __restrict__ out)
{
    __shared__ float red[256];
    const int t = threadIdx.x;

    float acc = 0.0f;
    for (int id = t; id < NIMG_PER * NBIN; id += 256) {
        const int i = id >> 8;
        const int r = id & 255;
        const float d = fabsf(bins[(size_t)i * NBIN + r]
                            - bins[(size_t)(NIMG_PER + i) * NBIN + r]);
        acc += d / cnt[r];
    }
    red[t] = acc;
    __syncthreads();
    for (int w = 128; w > 0; w >>= 1) {
        if (t < w) red[t] += red[t + w];
        __syncthreads();
    }
    if (t == 0) out[0] = red[0] / (float)(NIMG_PER * NBIN);
}

// ---------------------------------------------------------------------------
extern "C" void kernel_launch(void* const* d_in, const int* in_sizes, int n_in,
                              void* d_out, int out_size, void* d_ws, size_t ws_size,
                              hipStream_t stream)
{
    const float* pred = (const float*)d_in[0];
    const float* targ = (const float*)d_in[1];
    float* out = (float*)d_out;

    char* ws = (char*)d_ws;
    float* cnt   = (float*)ws;                                  // 256
    float* bins  = cnt + NBIN;                                  // 192*256
    float* bins2 = bins + (size_t)NIMG * NBIN;                  // 33*192*256
    const size_t fixed_f = NBIN + (size_t)NIMG*NBIN + (size_t)NTILE*NIMG*NBIN;
    const size_t off = (fixed_f*sizeof(float) + 255) & ~(size_t)255;
    float2* cbuf = (float2*)(ws + off);

    const size_t per_img = (size_t)IMGC * sizeof(float2);       // ~1.05 MiB
    size_t avail = (ws_size > off) ? (ws_size - off) : 0;
    int chunk = (int)(avail / per_img);
    if (chunk > NIMG) chunk = NIMG;
    if (chunk < 1) chunk = 1;

    hipMemsetAsync(cnt, 0, NBIN * sizeof(float), stream);
    counts_kernel<<<dim3(64), dim3(256), 0, stream>>>(cnt);

    for (int base = 0; base < NIMG; base += chunk) {
        const int n = (NIMG - base < chunk) ? (NIMG - base) : chunk;
        dim3 gA(HH / 8, n), gB(NTILE, n), blk(256);
        rowfft_kernel<<<gA, blk, 0, stream>>>(pred, targ, cbuf, base);
        colfft_kernel<<<gB, blk, 0, stream>>>(cbuf, bins2, base);
    }

    reduce_kernel<<<dim3(NIMG), dim3(256), 0, stream>>>(bins2, bins);
    finalize_kernel<<<dim3(1), dim3(256), 0, stream>>>(bins, cnt, out);
}

// Round 8
// 234.612 us; speedup vs baseline: 1.1391x; 1.1391x over previous
//
#include <hip/hip_runtime.h>
#include <math.h>

#define HH 512
#define WW 512
#define IMG (HH*WW)
#define NIMG_PER 96   // B*C = 32*3
#define NIMG 192      // pred + targ
#define NBIN 256      // max_r
#define EPSV 1e-8f
#define LN2F 0.69314718055994530942f

#define CSTR 264               // padded column count (257 used + 7 zero pad)
#define IMGC (512*CSTR)        // float2 per image, row-major [y][kx]
#define NTILE 33               // 8-column tiles
#define SLOT 580               // per-FFT LDS stride in float2; fsw(511)=574<580

// octal-digit reversal of 9-bit index (3 radix-8 stages)
__device__ __forceinline__ int drev(int s) {
    return ((s & 7) << 6) | (s & 56) | (s >> 6);
}
// bank swizzle on float2 element index
__device__ __forceinline__ int fsw(int a) { return a + (a >> 3); }

__device__ __forceinline__ float2 cmul(float2 a, float2 b) {
    return make_float2(a.x*b.x - a.y*b.y, a.x*b.y + a.y*b.x);
}
#define C_ADD(a,b) make_float2((a).x+(b).x, (a).y+(b).y)
#define C_SUB(a,b) make_float2((a).x-(b).x, (a).y-(b).y)
#define C_NI(a)    make_float2((a).y, -(a).x)   // * (-i)

// intra-wave "barrier": LDS is in-order per wave; stop compiler reordering
__device__ __forceinline__ void wsync() {
    asm volatile("" ::: "memory");
    __builtin_amdgcn_wave_barrier();
    asm volatile("" ::: "memory");
}

// radix-8 DIF butterfly, negative exponent
__device__ __forceinline__ void bfly8(float2 x[8]) {
    const float R = 0.70710678118654752440f;
    float2 t0=C_ADD(x[0],x[4]), t4=C_SUB(x[0],x[4]);
    float2 t1=C_ADD(x[1],x[5]), t5=C_SUB(x[1],x[5]);
    float2 t2=C_ADD(x[2],x[6]), t6=C_SUB(x[2],x[6]);
    float2 t3=C_ADD(x[3],x[7]), t7=C_SUB(x[3],x[7]);
    float2 u0=C_ADD(t0,t2), u2=C_SUB(t0,t2);
    float2 u1=C_ADD(t1,t3), u3=C_SUB(t1,t3);
    x[0]=C_ADD(u0,u1); x[4]=C_SUB(u0,u1);
    { float2 n3 = C_NI(u3); x[2]=C_ADD(u2,n3); x[6]=C_SUB(u2,n3); }
    float2 s1 = make_float2(R*(t5.x + t5.y), R*(t5.y - t5.x));   // * (R - iR)
    float2 s2 = C_NI(t6);
    float2 s3 = make_float2(R*(t7.y - t7.x), -R*(t7.x + t7.y));  // * (-R - iR)
    float2 v0=C_ADD(t4,s2), v2=C_SUB(t4,s2);
    float2 v1=C_ADD(s1,s3), v3=C_SUB(s1,s3);
    x[1]=C_ADD(v0,v1); x[5]=C_SUB(v0,v1);
    { float2 n3 = C_NI(v3); x[3]=C_ADD(v2,n3); x[7]=C_SUB(v2,n3); }
}

// x[j] *= w^j, w = exp(i*ang); chain depth 3 for ILP
__device__ __forceinline__ void twiddle7(float2* x, float ang) {
    const float sn = __sinf(ang), cs = __cosf(ang);
    const float2 w1 = make_float2(cs, sn);
    const float2 w2 = cmul(w1, w1);
    const float2 w3 = cmul(w2, w1);
    const float2 w4 = cmul(w2, w2);
    const float2 w5 = cmul(w2, w3);
    const float2 w6 = cmul(w3, w3);
    const float2 w7 = cmul(w3, w4);
    x[1]=cmul(x[1],w1); x[2]=cmul(x[2],w2); x[3]=cmul(x[3],w3);
    x[4]=cmul(x[4],w4); x[5]=cmul(x[5],w5); x[6]=cmul(x[6],w6);
    x[7]=cmul(x[7],w7);
}

// ---------------------------------------------------------------------------
// Pass A: 512-thr block = 8 waves = 8 row-pairs (16 image rows), ZERO block
// barriers. Per wave: stage-1 direct from global (coalesced stride-64 f32),
// radix-8 DIF FFT in own LDS slot, Hermitian unpack at consecutive-k per
// lane -> directly coalesced [y][kx] global writes.
// ---------------------------------------------------------------------------
__global__ __launch_bounds__(512) void rowfft_kernel(
    const float* __restrict__ pred, const float* __restrict__ targ,
    float2* __restrict__ out, int img_base)
{
    __shared__ float2 sd[8*SLOT];
    const int t    = threadIdx.x;
    const int lane = t & 63;
    const int w    = t >> 6;

    const int pb = blockIdx.x;          // rows pb*16 .. pb*16+15
    const int li = blockIdx.y;
    const int g  = img_base + li;
    const float* img = (g < NIMG_PER) ? (pred + (size_t)g * IMG)
                                      : (targ + (size_t)(g - NIMG_PER) * IMG);
    const float* rowA = img + (size_t)(pb*16 + 2*w) * WW;
    const float* rowB = rowA + WW;

    float2* p = sd + w * SLOT;
    float2 x[8];
    const int i = lane;

    // ---- stage 1: load direct from global (lane-coalesced), bfly, twiddle
    #pragma unroll
    for (int j = 0; j < 8; ++j)
        x[j] = make_float2(rowA[i + 64*j], rowB[i + 64*j]);
    bfly8(x);
    twiddle7(x, -0.012271846303085130f * (float)i);       // -2pi/512 * i
    #pragma unroll
    for (int j = 0; j < 8; ++j) p[fsw(i + 64*j)] = x[j];
    wsync();

    // ---- stage 2: groups of 64
    const int grp = i >> 3, i2 = i & 7;
    #pragma unroll
    for (int j = 0; j < 8; ++j) x[j] = p[fsw(64*grp + i2 + 8*j)];
    bfly8(x);
    twiddle7(x, -0.098174770424681038f * (float)i2);      // -2pi/64 * i2
    #pragma unroll
    for (int j = 0; j < 8; ++j) p[fsw(64*grp + i2 + 8*j)] = x[j];
    wsync();

    // ---- stage 3: contiguous 8
    #pragma unroll
    for (int j = 0; j < 8; ++j) x[j] = p[fsw(8*i + j)];
    bfly8(x);
    #pragma unroll
    for (int j = 0; j < 8; ++j) p[fsw(8*i + j)] = x[j];
    wsync();

    // ---- Hermitian unpack, consecutive k per lane -> coalesced stores.
    // General formula handles k=0 and k=256 self-pairs (a2 == a1).
    float2* dstA = out + (size_t)li * IMGC + (size_t)(pb*16 + 2*w) * CSTR;
    float2* dstB = dstA + CSTR;
    #pragma unroll
    for (int it = 0; it < 5; ++it) {
        const int k = it*64 + lane;
        if (k <= 256) {
            const float2 P = p[fsw(drev(k))];
            const float2 Q = p[fsw(drev((512 - k) & 511))];
            dstA[k] = make_float2(0.5f*(P.x + Q.x), 0.5f*(P.y - Q.y));
            dstB[k] = make_float2(0.5f*(P.y + Q.y), 0.5f*(Q.x - P.x));
        } else if (k < CSTR) {          // zero the 7 pad columns
            dstA[k] = make_float2(0.0f, 0.0f);
            dstB[k] = make_float2(0.0f, 0.0f);
        }
    }
}

// ---------------------------------------------------------------------------
// Pass B: 512-thr block = 8 waves, tile of 8 columns, ONE column per wave.
// Coalesced block staging (64B/row), then wave-local FFT + run-binning.
// Two block barriers total (post-staging, pre-merge).
// ---------------------------------------------------------------------------
__global__ __launch_bounds__(512) void colfft_kernel(
    const float2* __restrict__ in, float* __restrict__ bins2, int img_base)
{
    __shared__ float2 sd[8*SLOT];
    __shared__ float  bs[8*257];      // one replica per wave
    const int t    = threadIdx.x;
    const int lane = t & 63;
    const int w    = t >> 6;

    for (int id = lane; id < 257; id += 64) bs[w*257 + id] = 0.0f;

    const int li = blockIdx.y;
    const int x0 = blockIdx.x * 8;
    const float2* src = in + (size_t)li * IMGC;

    // staging: 8 cols x 512 rows, 64B per row -> full cachelines
    #pragma unroll
    for (int it = 0; it < 8; ++it) {
        const int id = it*512 + t;        // 0..4095
        const int y  = id >> 3;
        const int cl = id & 7;
        sd[cl*SLOT + fsw(y)] = src[(size_t)y * CSTR + (x0 + cl)];
    }
    __syncthreads();

    // wave w owns column x0+w end-to-end
    float2* p = sd + w * SLOT;
    float2 x[8];
    const int i = lane;

    // ---- stage 1
    #pragma unroll
    for (int j = 0; j < 8; ++j) x[j] = p[fsw(i + 64*j)];
    bfly8(x);
    twiddle7(x, -0.012271846303085130f * (float)i);
    #pragma unroll
    for (int j = 0; j < 8; ++j) p[fsw(i + 64*j)] = x[j];
    wsync();

    // ---- stage 2
    const int grp = i >> 3, i2 = i & 7;
    #pragma unroll
    for (int j = 0; j < 8; ++j) x[j] = p[fsw(64*grp + i2 + 8*j)];
    bfly8(x);
    twiddle7(x, -0.098174770424681038f * (float)i2);
    #pragma unroll
    for (int j = 0; j < 8; ++j) p[fsw(64*grp + i2 + 8*j)] = x[j];
    wsync();

    // ---- stage 3 + writeback (enables consecutive-ky regather)
    #pragma unroll
    for (int j = 0; j < 8; ++j) x[j] = p[fsw(8*i + j)];
    bfly8(x);
    #pragma unroll
    for (int j = 0; j < 8; ++j) p[fsw(8*i + j)] = x[j];
    wsync();

    // ---- binning: lane h owns ky = 8h..8h+7; run-accumulate (bins are
    // piecewise-constant along consecutive ky), LDS atomic per bin change.
    // Values in log2; final scalar scaled by ln2 in finalize.
    {
        const int h  = lane;
        const int kx = x0 + w;
        const bool valid = (kx <= 256);
        const float scale = (kx == 0 || kx == 256) ? 0.5f : 1.0f;
        const int dxsq = (kx - 256) * (kx - 256);
        float* bsw = bs + w*257;

        float acc = 0.0f;
        int prevb = 1000;
        #pragma unroll
        for (int j = 0; j < 8; ++j) {
            const int q = 64*j + 8*(h & 7) + (h >> 3);    // = drev(8h+j)
            const float2 v = p[fsw(q)];
            const float val = __log2f(v.x*v.x + v.y*v.y + EPSV) * scale;
            const int dy = 8*h + j - 256;
            const int b  = (int)sqrtf((float)(dy*dy + dxsq));
            if (b != prevb) {
                if (prevb < NBIN && valid) atomicAdd(&bsw[prevb], acc);
                prevb = b; acc = val;
            } else {
                acc += val;
            }
        }
        if (prevb < NBIN && valid) atomicAdd(&bsw[prevb], acc);
    }
    __syncthreads();

    if (t < NBIN) {
        float v = 0.0f;
        #pragma unroll
        for (int r = 0; r < 8; ++r) v += bs[r*257 + t];
        bins2[((size_t)blockIdx.x * NIMG + (img_base + li)) * NBIN + t] = 2.0f * v;
    }
}

// ---------------------------------------------------------------------------
// Reduce the 33 per-tile slices into bins[img][bin].
// ---------------------------------------------------------------------------
__global__ __launch_bounds__(256) void reduce_kernel(
    const float* __restrict__ bins2, float* __restrict__ bins)
{
    const int li = blockIdx.x;
    const int t  = threadIdx.x;
    float s = 0.0f;
    #pragma unroll
    for (int tile = 0; tile < NTILE; ++tile)
        s += bins2[((size_t)tile * NIMG + li) * NBIN + t];
    bins[(size_t)li * NBIN + t] = s;
}

// ---------------------------------------------------------------------------
__global__ __launch_bounds__(256) void counts_kernel(float* __restrict__ cnt)
{
    __shared__ float c[NBIN];
    const int t = threadIdx.x;
    c[t] = 0.0f;
    __syncthreads();

    const int base = blockIdx.x * 4096;
    #pragma unroll
    for (int i = 0; i < 16; ++i) {
        const int id = base + i * 256 + t;
        const int y = id >> 9, xx = id & 511;
        const int dy = y - 256, dx = xx - 256;
        const int b  = (int)sqrtf((float)(dy*dy + dx*dx));
        if (b < NBIN) atomicAdd(&c[b], 1.0f);
    }
    __syncthreads();
    if (c[t] != 0.0f) atomicAdd(&cnt[t], c[t]);
}

// ---------------------------------------------------------------------------
// Finalize: mean over (pair, bin) of |sum_p - sum_t| / cnt, times ln2
// (bins hold log2 sums; ln = ln2 * log2 and everything downstream is
// positively-homogeneous).
// ---------------------------------------------------------------------------
__global__ __launch_bounds__(256) void finalize_kernel(
    const float* __restrict__ bins, const float* __restrict__ cnt,
    float* __restrict__ out)
{
    __shared__ float red[256];
    const int t = threadIdx.x;

    float acc = 0.0f;
    for (int id = t; id < NIMG_PER * NBIN; id += 256) {
        const int i = id >> 8;
        const int r = id & 255;
        const float d = fabsf(bins[(size_t)i * NBIN + r]
                            - bins[(size_t)(NIMG_PER + i) * NBIN + r]);
        acc += d / cnt[r];
    }
    red[t] = acc;
    __syncthreads();
    for (int w = 128; w > 0; w >>= 1) {
        if (t < w) red[t] += red[t + w];
        __syncthreads();
    }
    if (t == 0) out[0] = red[0] * (LN2F / (float)(NIMG_PER * NBIN));
}

// ---------------------------------------------------------------------------
extern "C" void kernel_launch(void* const* d_in, const int* in_sizes, int n_in,
                              void* d_out, int out_size, void* d_ws, size_t ws_size,
                              hipStream_t stream)
{
    const float* pred = (const float*)d_in[0];
    const float* targ = (const float*)d_in[1];
    float* out = (float*)d_out;

    char* ws = (char*)d_ws;
    float* cnt   = (float*)ws;                                  // 256
    float* bins  = cnt + NBIN;                                  // 192*256
    float* bins2 = bins + (size_t)NIMG * NBIN;                  // 33*192*256
    const size_t fixed_f = NBIN + (size_t)NIMG*NBIN + (size_t)NTILE*NIMG*NBIN;
    const size_t off = (fixed_f*sizeof(float) + 255) & ~(size_t)255;
    float2* cbuf = (float2*)(ws + off);

    const size_t per_img = (size_t)IMGC * sizeof(float2);       // ~1.08 MiB
    size_t avail = (ws_size > off) ? (ws_size - off) : 0;
    int chunk = (int)(avail / per_img);
    if (chunk > NIMG) chunk = NIMG;
    if (chunk < 1) chunk = 1;

    hipMemsetAsync(cnt, 0, NBIN * sizeof(float), stream);
    counts_kernel<<<dim3(64), dim3(256), 0, stream>>>(cnt);

    for (int base = 0; base < NIMG; base += chunk) {
        const int n = (NIMG - base < chunk) ? (NIMG - base) : chunk;
        dim3 gA(HH / 16, n), gB(NTILE, n);
        rowfft_kernel<<<gA, dim3(512), 0, stream>>>(pred, targ, cbuf, base);
        colfft_kernel<<<gB, dim3(512), 0, stream>>>(cbuf, bins2, base);
    }

    reduce_kernel<<<dim3(NIMG), dim3(256), 0, stream>>>(bins2, bins);
    finalize_kernel<<<dim3(1), dim3(256), 0, stream>>>(bins, cnt, out);
}

// Round 9
// 234.271 us; speedup vs baseline: 1.1407x; 1.0015x over previous
//
#include <hip/hip_runtime.h>
#include <math.h>

#define HH 512
#define WW 512
#define IMG (HH*WW)
#define NIMG_PER 96   // B*C = 32*3
#define NIMG 192      // pred + targ
#define NBIN 256      // max_r
#define EPSV 1e-8f
#define LN2F 0.69314718055994530942f

#define CSTR 264               // padded column count (257 used + 7 zero pad)
#define IMGC (512*CSTR)        // float2 per image, row-major [y][kx]
#define NTILE 33               // 8-column tiles
#define SLOT 575               // per-FFT LDS stride in float2; fsw(511)=574<575

// octal-digit reversal of 9-bit index (3 radix-8 stages)
__device__ __forceinline__ int drev(int s) {
    return ((s & 7) << 6) | (s & 56) | (s >> 6);
}
// bank swizzle on float2 element index
__device__ __forceinline__ int fsw(int a) { return a + (a >> 3); }

__device__ __forceinline__ float2 cmul(float2 a, float2 b) {
    return make_float2(a.x*b.x - a.y*b.y, a.x*b.y + a.y*b.x);
}
#define C_ADD(a,b) make_float2((a).x+(b).x, (a).y+(b).y)
#define C_SUB(a,b) make_float2((a).x-(b).x, (a).y-(b).y)
#define C_NI(a)    make_float2((a).y, -(a).x)   // * (-i)

// intra-wave "barrier": LDS is in-order per wave; stop compiler reordering
__device__ __forceinline__ void wsync() {
    asm volatile("" ::: "memory");
    __builtin_amdgcn_wave_barrier();
    asm volatile("" ::: "memory");
}

// radix-8 DIF butterfly, negative exponent
__device__ __forceinline__ void bfly8(float2 x[8]) {
    const float R = 0.70710678118654752440f;
    float2 t0=C_ADD(x[0],x[4]), t4=C_SUB(x[0],x[4]);
    float2 t1=C_ADD(x[1],x[5]), t5=C_SUB(x[1],x[5]);
    float2 t2=C_ADD(x[2],x[6]), t6=C_SUB(x[2],x[6]);
    float2 t3=C_ADD(x[3],x[7]), t7=C_SUB(x[3],x[7]);
    float2 u0=C_ADD(t0,t2), u2=C_SUB(t0,t2);
    float2 u1=C_ADD(t1,t3), u3=C_SUB(t1,t3);
    x[0]=C_ADD(u0,u1); x[4]=C_SUB(u0,u1);
    { float2 n3 = C_NI(u3); x[2]=C_ADD(u2,n3); x[6]=C_SUB(u2,n3); }
    float2 s1 = make_float2(R*(t5.x + t5.y), R*(t5.y - t5.x));   // * (R - iR)
    float2 s2 = C_NI(t6);
    float2 s3 = make_float2(R*(t7.y - t7.x), -R*(t7.x + t7.y));  // * (-R - iR)
    float2 v0=C_ADD(t4,s2), v2=C_SUB(t4,s2);
    float2 v1=C_ADD(s1,s3), v3=C_SUB(s1,s3);
    x[1]=C_ADD(v0,v1); x[5]=C_SUB(v0,v1);
    { float2 n3 = C_NI(v3); x[3]=C_ADD(v2,n3); x[7]=C_SUB(v2,n3); }
}

// x[j] *= w^j, w = exp(i*ang); chain depth 3 for ILP
__device__ __forceinline__ void twiddle7(float2* x, float ang) {
    const float sn = __sinf(ang), cs = __cosf(ang);
    const float2 w1 = make_float2(cs, sn);
    const float2 w2 = cmul(w1, w1);
    const float2 w3 = cmul(w2, w1);
    const float2 w4 = cmul(w2, w2);
    const float2 w5 = cmul(w2, w3);
    const float2 w6 = cmul(w3, w3);
    const float2 w7 = cmul(w3, w4);
    x[1]=cmul(x[1],w1); x[2]=cmul(x[2],w2); x[3]=cmul(x[3],w3);
    x[4]=cmul(x[4],w4); x[5]=cmul(x[5],w5); x[6]=cmul(x[6],w6);
    x[7]=cmul(x[7],w7);
}

// ---------------------------------------------------------------------------
// Pass A: 512-thr block = 8 waves = 8 row-pairs (16 image rows), ZERO block
// barriers. Stage-1 direct from global; all LDS ops are base + immediate
// offset (fsw identities: fsw(i+64j)=fsw(i)+72j, fsw(64g+i2+8j)=72g+i2+9j,
// fsw(8i+j)=9i+j). Hermitian unpack -> coalesced [y][kx] stores.
// ---------------------------------------------------------------------------
__global__ __launch_bounds__(512) void rowfft_kernel(
    const float* __restrict__ pred, const float* __restrict__ targ,
    float2* __restrict__ out, int img_base)
{
    __shared__ float2 sd[8*SLOT];
    const int t    = threadIdx.x;
    const int lane = t & 63;
    const int w    = t >> 6;

    const int pb = blockIdx.x;          // rows pb*16 .. pb*16+15
    const int li = blockIdx.y;
    const int g  = img_base + li;
    const float* img = (g < NIMG_PER) ? (pred + (size_t)g * IMG)
                                      : (targ + (size_t)(g - NIMG_PER) * IMG);
    const float* rowA = img + (size_t)(pb*16 + 2*w) * WW + lane;
    const float* rowB = rowA + WW;

    float2* p = sd + w * SLOT;
    float2 x[8];
    const int i = lane;

    // ---- stage 1: global->reg (coalesced, immediate offsets), bfly, twiddle
    #pragma unroll
    for (int j = 0; j < 8; ++j)
        x[j] = make_float2(rowA[64*j], rowB[64*j]);
    bfly8(x);
    twiddle7(x, -0.012271846303085130f * (float)i);       // -2pi/512 * i
    {
        float2* q = p + fsw(i);
        #pragma unroll
        for (int j = 0; j < 8; ++j) q[72*j] = x[j];
    }
    wsync();

    // ---- stage 2
    {
        float2* q = p + 72*(i >> 3) + (i & 7);
        #pragma unroll
        for (int j = 0; j < 8; ++j) x[j] = q[9*j];
        bfly8(x);
        twiddle7(x, -0.098174770424681038f * (float)(i & 7));   // -2pi/64 * i2
        #pragma unroll
        for (int j = 0; j < 8; ++j) q[9*j] = x[j];
    }
    wsync();

    // ---- stage 3: contiguous
    {
        float2* q = p + 9*i;
        #pragma unroll
        for (int j = 0; j < 8; ++j) x[j] = q[j];
        bfly8(x);
        #pragma unroll
        for (int j = 0; j < 8; ++j) q[j] = x[j];
    }
    wsync();

    // ---- Hermitian unpack, consecutive k per lane -> coalesced stores.
    float2* dstA = out + (size_t)li * IMGC + (size_t)(pb*16 + 2*w) * CSTR;
    float2* dstB = dstA + CSTR;
    #pragma unroll
    for (int it = 0; it < 5; ++it) {
        const int k = it*64 + lane;
        if (k <= 256) {
            const float2 P = p[fsw(drev(k))];
            const float2 Q = p[fsw(drev((512 - k) & 511))];
            dstA[k] = make_float2(0.5f*(P.x + Q.x), 0.5f*(P.y - Q.y));
            dstB[k] = make_float2(0.5f*(P.y + Q.y), 0.5f*(Q.x - P.x));
        } else if (k < CSTR) {          // zero the 7 pad columns
            dstA[k] = make_float2(0.0f, 0.0f);
            dstB[k] = make_float2(0.0f, 0.0f);
        }
    }
}

// ---------------------------------------------------------------------------
// Pass B: 512-thr block = 8 waves, 8-column tile, ONE column per wave.
// float4 staging (2 cols/lane, full-cacheline rows), base+immediate LDS ops,
// run-binning with float-FMA radius, 4 shared bin replicas (40.2 KB LDS ->
// 4 blocks/CU). Two block barriers total.
// ---------------------------------------------------------------------------
__global__ __launch_bounds__(512) void colfft_kernel(
    const float2* __restrict__ in, float* __restrict__ bins2, int img_base)
{
    __shared__ float2 sd[8*SLOT];
    __shared__ float  bs[4*257];      // replica w&3 (waves w, w+4 share)
    const int t    = threadIdx.x;
    const int lane = t & 63;
    const int w    = t >> 6;

    for (int id = t; id < 4*257; id += 512) bs[id] = 0.0f;

    const int li = blockIdx.y;
    const int x0 = blockIdx.x * 8;
    // staging: lane loads float4 = 2 adjacent columns at one row
    {
        const int y0  = t >> 2;            // 0..127
        const int clp = t & 3;             // column pair 0..3
        const float4* gsrc = (const float4*)(in + (size_t)li * IMGC + x0)
                           + (size_t)y0 * (CSTR/2) + clp;
        float2* dA = sd + (2*clp)*SLOT + fsw(y0);
        float2* dB = dA + SLOT;
        #pragma unroll
        for (int it = 0; it < 4; ++it) {   // y = y0 + 128*it; fsw -> +144*it
            const float4 v = gsrc[(size_t)it * 128 * (CSTR/2)];
            dA[144*it] = make_float2(v.x, v.y);
            dB[144*it] = make_float2(v.z, v.w);
        }
    }
    __syncthreads();

    // wave w owns column x0+w end-to-end
    float2* p = sd + w * SLOT;
    float2 x[8];
    const int i = lane;

    // ---- stage 1
    {
        float2* q = p + fsw(i);
        #pragma unroll
        for (int j = 0; j < 8; ++j) x[j] = q[72*j];
        bfly8(x);
        twiddle7(x, -0.012271846303085130f * (float)i);
        #pragma unroll
        for (int j = 0; j < 8; ++j) q[72*j] = x[j];
    }
    wsync();

    // ---- stage 2
    {
        float2* q = p + 72*(i >> 3) + (i & 7);
        #pragma unroll
        for (int j = 0; j < 8; ++j) x[j] = q[9*j];
        bfly8(x);
        twiddle7(x, -0.098174770424681038f * (float)(i & 7));
        #pragma unroll
        for (int j = 0; j < 8; ++j) q[9*j] = x[j];
    }
    wsync();

    // ---- stage 3 + writeback (enables consecutive-ky regather)
    {
        float2* q = p + 9*i;
        #pragma unroll
        for (int j = 0; j < 8; ++j) x[j] = q[j];
        bfly8(x);
        #pragma unroll
        for (int j = 0; j < 8; ++j) q[j] = x[j];
    }
    wsync();

    // ---- binning: lane h owns ky = 8h..8h+7 (storage fsw(c)+72j);
    // run-accumulate, LDS atomic per bin change; float-FMA radius (exact).
    {
        const int h  = lane;
        const int kx = x0 + w;
        const bool valid = (kx <= 256);
        const float scale = (kx == 0 || kx == 256) ? 0.5f : 1.0f;
        const float dxf = (float)((kx - 256) * (kx - 256));
        float* bsw = bs + (w & 3) * 257;
        float2* qb = p + fsw(8*(h & 7) + (h >> 3));
        float dyf = (float)(8*h - 256);

        float acc = 0.0f;
        int prevb = 1000;
        #pragma unroll
        for (int j = 0; j < 8; ++j) {
            const float2 v = qb[72*j];
            const float val = __log2f(v.x*v.x + v.y*v.y + EPSV) * scale;
            const int b = (int)sqrtf(fmaf(dyf, dyf, dxf));
            dyf += 1.0f;
            if (b != prevb) {
                if (prevb < NBIN && valid) atomicAdd(&bsw[prevb], acc);
                prevb = b; acc = val;
            } else {
                acc += val;
            }
        }
        if (prevb < NBIN && valid) atomicAdd(&bsw[prevb], acc);
    }
    __syncthreads();

    if (t < NBIN) {
        float v = 0.0f;
        #pragma unroll
        for (int r = 0; r < 4; ++r) v += bs[r*257 + t];
        bins2[((size_t)blockIdx.x * NIMG + (img_base + li)) * NBIN + t] = 2.0f * v;
    }
}

// ---------------------------------------------------------------------------
// Reduce the 33 per-tile slices into bins[img][bin].
// ---------------------------------------------------------------------------
__global__ __launch_bounds__(256) void reduce_kernel(
    const float* __restrict__ bins2, float* __restrict__ bins)
{
    const int li = blockIdx.x;
    const int t  = threadIdx.x;
    float s = 0.0f;
    #pragma unroll
    for (int tile = 0; tile < NTILE; ++tile)
        s += bins2[((size_t)tile * NIMG + li) * NBIN + t];
    bins[(size_t)li * NBIN + t] = s;
}

// ---------------------------------------------------------------------------
__global__ __launch_bounds__(256) void counts_kernel(float* __restrict__ cnt)
{
    __shared__ float c[NBIN];
    const int t = threadIdx.x;
    c[t] = 0.0f;
    __syncthreads();

    const int base = blockIdx.x * 4096;
    #pragma unroll
    for (int i = 0; i < 16; ++i) {
        const int id = base + i * 256 + t;
        const int y = id >> 9, xx = id & 511;
        const int dy = y - 256, dx = xx - 256;
        const int b  = (int)sqrtf((float)(dy*dy + dx*dx));
        if (b < NBIN) atomicAdd(&c[b], 1.0f);
    }
    __syncthreads();
    if (c[t] != 0.0f) atomicAdd(&cnt[t], c[t]);
}

// ---------------------------------------------------------------------------
// Finalize: mean over (pair, bin) of |sum_p - sum_t| / cnt, times ln2
// (bins hold log2 sums; everything downstream is positively homogeneous).
// ---------------------------------------------------------------------------
__global__ __launch_bounds__(256) void finalize_kernel(
    const float* __restrict__ bins, const float* __restrict__ cnt,
    float* __restrict__ out)
{
    __shared__ float red[256];
    const int t = threadIdx.x;

    float acc = 0.0f;
    for (int id = t; id < NIMG_PER * NBIN; id += 256) {
        const int i = id >> 8;
        const int r = id & 255;
        const float d = fabsf(bins[(size_t)i * NBIN + r]
                            - bins[(size_t)(NIMG_PER + i) * NBIN + r]);
        acc += d / cnt[r];
    }
    red[t] = acc;
    __syncthreads();
    for (int w = 128; w > 0; w >>= 1) {
        if (t < w) red[t] += red[t + w];
        __syncthreads();
    }
    if (t == 0) out[0] = red[0] * (LN2F / (float)(NIMG_PER * NBIN));
}

// ---------------------------------------------------------------------------
extern "C" void kernel_launch(void* const* d_in, const int* in_sizes, int n_in,
                              void* d_out, int out_size, void* d_ws, size_t ws_size,
                              hipStream_t stream)
{
    const float* pred = (const float*)d_in[0];
    const float* targ = (const float*)d_in[1];
    float* out = (float*)d_out;

    char* ws = (char*)d_ws;
    float* cnt   = (float*)ws;                                  // 256
    float* bins  = cnt + NBIN;                                  // 192*256
    float* bins2 = bins + (size_t)NIMG * NBIN;                  // 33*192*256
    const size_t fixed_f = NBIN + (size_t)NIMG*NBIN + (size_t)NTILE*NIMG*NBIN;
    const size_t off = (fixed_f*sizeof(float) + 255) & ~(size_t)255;
    float2* cbuf = (float2*)(ws + off);

    const size_t per_img = (size_t)IMGC * sizeof(float2);       // ~1.08 MiB
    size_t avail = (ws_size > off) ? (ws_size - off) : 0;
    int chunk = (int)(avail / per_img);
    if (chunk > NIMG) chunk = NIMG;
    if (chunk < 1) chunk = 1;

    hipMemsetAsync(cnt, 0, NBIN * sizeof(float), stream);
    counts_kernel<<<dim3(64), dim3(256), 0, stream>>>(cnt);

    for (int base = 0; base < NIMG; base += chunk) {
        const int n = (NIMG - base < chunk) ? (NIMG - base) : chunk;
        dim3 gA(HH / 16, n), gB(NTILE, n);
        rowfft_kernel<<<gA, dim3(512), 0, stream>>>(pred, targ, cbuf, base);
        colfft_kernel<<<gB, dim3(512), 0, stream>>>(cbuf, bins2, base);
    }

    reduce_kernel<<<dim3(NIMG), dim3(256), 0, stream>>>(bins2, bins);
    finalize_kernel<<<dim3(1), dim3(256), 0, stream>>>(bins, cnt, out);
}

// Round 10
// 225.649 us; speedup vs baseline: 1.1843x; 1.0382x over previous
//
#include <hip/hip_runtime.h>
#include <math.h>

#define HH 512
#define WW 512
#define IMG (HH*WW)
#define NIMG_PER 96   // B*C = 32*3
#define NIMG 192      // pred + targ
#define NBIN 256      // max_r
#define EPSV 1e-8f
#define LN2F 0.69314718055994530942f

#define CSTR 264               // padded column count (257 used + 7 zero pad)
#define IMGC (512*CSTR)        // complex elems per image, row-major [y][kx]
#define NTILE 33               // 8-column tiles
#define SLOT 575               // per-FFT LDS stride; fsw(511)=574<575

typedef float v2f __attribute__((ext_vector_type(2)));   // packed-fp32 complex

// octal-digit reversal of 9-bit index (3 radix-8 stages)
__device__ __forceinline__ int drev(int s) {
    return ((s & 7) << 6) | (s & 56) | (s >> 6);
}
// bank swizzle on complex element index
__device__ __forceinline__ int fsw(int a) { return a + (a >> 3); }

// complex mul via packed ops: (a.x,a.x)*b + (a.y,a.y)*(-b.y,b.x)
__device__ __forceinline__ v2f cmul(v2f a, v2f b) {
    return (v2f){a.x, a.x} * b + (v2f){a.y, a.y} * (v2f){-b.y, b.x};
}
__device__ __forceinline__ v2f cni(v2f a) { return (v2f){a.y, -a.x}; }  // * -i

// intra-wave "barrier": LDS is in-order per wave; stop compiler reordering
__device__ __forceinline__ void wsync() {
    asm volatile("" ::: "memory");
    __builtin_amdgcn_wave_barrier();
    asm volatile("" ::: "memory");
}

// radix-8 DIF butterfly, negative exponent — all packed-2 fp32 ops
__device__ __forceinline__ void bfly8(v2f x[8]) {
    const float R = 0.70710678118654752440f;
    v2f t0=x[0]+x[4], t4=x[0]-x[4];
    v2f t1=x[1]+x[5], t5=x[1]-x[5];
    v2f t2=x[2]+x[6], t6=x[2]-x[6];
    v2f t3=x[3]+x[7], t7=x[3]-x[7];
    v2f u0=t0+t2, u2=t0-t2;
    v2f u1=t1+t3, u3=t1-t3;
    x[0]=u0+u1; x[4]=u0-u1;
    { v2f n3 = cni(u3); x[2]=u2+n3; x[6]=u2-n3; }
    // s1 = t5*(R-iR) = R*(x+y, y-x); s3 = t7*(-R-iR) = R*(y-x, -x-y)
    v2f s1 = (v2f){R, R} * ((v2f){t5.x, t5.y} + (v2f){t5.y, -t5.x});
    v2f s2 = cni(t6);
    v2f s3 = (v2f){R, R} * ((v2f){t7.y, -t7.x} - (v2f){t7.x, t7.y});
    v2f v0=t4+s2, v2_=t4-s2;
    v2f v1=s1+s3, v3=s1-s3;
    x[1]=v0+v1; x[5]=v0-v1;
    { v2f m3 = cni(v3); x[3]=v2_+m3; x[7]=v2_-m3; }
}

// x[j] *= w^j, w = exp(i*ang); chain depth 3 for ILP
__device__ __forceinline__ void twiddle7(v2f* x, float ang) {
    const float sn = __sinf(ang), cs = __cosf(ang);
    const v2f w1 = (v2f){cs, sn};
    const v2f w2 = cmul(w1, w1);
    const v2f w3 = cmul(w2, w1);
    const v2f w4 = cmul(w2, w2);
    const v2f w5 = cmul(w2, w3);
    const v2f w6 = cmul(w3, w3);
    const v2f w7 = cmul(w3, w4);
    x[1]=cmul(x[1],w1); x[2]=cmul(x[2],w2); x[3]=cmul(x[3],w3);
    x[4]=cmul(x[4],w4); x[5]=cmul(x[5],w5); x[6]=cmul(x[6],w6);
    x[7]=cmul(x[7],w7);
}

// ---------------------------------------------------------------------------
// Pass A: 512-thr block = 8 waves = 8 row-pairs (16 image rows), ZERO block
// barriers. Stage-1 direct from global; base+immediate LDS ops
// (fsw(i+64j)=fsw(i)+72j, fsw(64g+i2+8j)=72g+i2+9j, fsw(8i+j)=9i+j).
// Hermitian unpack -> coalesced [y][kx] stores.
// ---------------------------------------------------------------------------
__global__ __launch_bounds__(512) void rowfft_kernel(
    const float* __restrict__ pred, const float* __restrict__ targ,
    v2f* __restrict__ out, int img_base)
{
    __shared__ v2f sd[8*SLOT];
    const int t    = threadIdx.x;
    const int lane = t & 63;
    const int w    = t >> 6;

    const int pb = blockIdx.x;          // rows pb*16 .. pb*16+15
    const int li = blockIdx.y;
    const int g  = img_base + li;
    const float* img = (g < NIMG_PER) ? (pred + (size_t)g * IMG)
                                      : (targ + (size_t)(g - NIMG_PER) * IMG);
    const float* rowA = img + (size_t)(pb*16 + 2*w) * WW + lane;
    const float* rowB = rowA + WW;

    v2f* p = sd + w * SLOT;
    v2f x[8];
    const int i = lane;

    // ---- stage 1: global->reg (coalesced, immediate offsets), bfly, twiddle
    #pragma unroll
    for (int j = 0; j < 8; ++j)
        x[j] = (v2f){rowA[64*j], rowB[64*j]};
    bfly8(x);
    twiddle7(x, -0.012271846303085130f * (float)i);       // -2pi/512 * i
    {
        v2f* q = p + fsw(i);
        #pragma unroll
        for (int j = 0; j < 8; ++j) q[72*j] = x[j];
    }
    wsync();

    // ---- stage 2
    {
        v2f* q = p + 72*(i >> 3) + (i & 7);
        #pragma unroll
        for (int j = 0; j < 8; ++j) x[j] = q[9*j];
        bfly8(x);
        twiddle7(x, -0.098174770424681038f * (float)(i & 7));   // -2pi/64 * i2
        #pragma unroll
        for (int j = 0; j < 8; ++j) q[9*j] = x[j];
    }
    wsync();

    // ---- stage 3: contiguous
    {
        v2f* q = p + 9*i;
        #pragma unroll
        for (int j = 0; j < 8; ++j) x[j] = q[j];
        bfly8(x);
        #pragma unroll
        for (int j = 0; j < 8; ++j) q[j] = x[j];
    }
    wsync();

    // ---- Hermitian unpack, consecutive k per lane -> coalesced stores.
    // Fa = 0.5*(P + (Q.x,-Q.y)); Fb = 0.5*((P.y,-P.x) + (Q.y,Q.x))
    v2f* dstA = out + (size_t)li * IMGC + (size_t)(pb*16 + 2*w) * CSTR;
    v2f* dstB = dstA + CSTR;
    #pragma unroll
    for (int it = 0; it < 5; ++it) {
        const int k = it*64 + lane;
        if (k <= 256) {
            const v2f P = p[fsw(drev(k))];
            const v2f Q = p[fsw(drev((512 - k) & 511))];
            dstA[k] = (v2f){0.5f, 0.5f} * (P + (v2f){Q.x, -Q.y});
            dstB[k] = (v2f){0.5f, 0.5f} * ((v2f){P.y, -P.x} + (v2f){Q.y, Q.x});
        } else if (k < CSTR) {          // zero the 7 pad columns
            dstA[k] = (v2f){0.0f, 0.0f};
            dstB[k] = (v2f){0.0f, 0.0f};
        }
    }
}

// ---------------------------------------------------------------------------
// Pass B: 512-thr block = 8 waves, 8-column tile, ONE column per wave.
// float4 staging (2 cols/lane), base+immediate LDS ops, run-binning with
// float-FMA radius, 4 shared bin replicas. Two block barriers total.
// ---------------------------------------------------------------------------
__global__ __launch_bounds__(512) void colfft_kernel(
    const v2f* __restrict__ in, float* __restrict__ bins2, int img_base)
{
    __shared__ v2f sd[8*SLOT];
    __shared__ float bs[4*257];       // replica w&3 (waves w, w+4 share)
    const int t    = threadIdx.x;
    const int lane = t & 63;
    const int w    = t >> 6;

    for (int id = t; id < 4*257; id += 512) bs[id] = 0.0f;

    const int li = blockIdx.y;
    const int x0 = blockIdx.x * 8;
    // staging: lane loads float4 = 2 adjacent columns at one row
    {
        const int y0  = t >> 2;            // 0..127
        const int clp = t & 3;             // column pair 0..3
        const float4* gsrc = (const float4*)(in + (size_t)li * IMGC + x0)
                           + (size_t)y0 * (CSTR/2) + clp;
        v2f* dA = sd + (2*clp)*SLOT + fsw(y0);
        v2f* dB = dA + SLOT;
        #pragma unroll
        for (int it = 0; it < 4; ++it) {   // y = y0 + 128*it; fsw -> +144*it
            const float4 v = gsrc[(size_t)it * 128 * (CSTR/2)];
            dA[144*it] = (v2f){v.x, v.y};
            dB[144*it] = (v2f){v.z, v.w};
        }
    }
    __syncthreads();

    // wave w owns column x0+w end-to-end
    v2f* p = sd + w * SLOT;
    v2f x[8];
    const int i = lane;

    // ---- stage 1
    {
        v2f* q = p + fsw(i);
        #pragma unroll
        for (int j = 0; j < 8; ++j) x[j] = q[72*j];
        bfly8(x);
        twiddle7(x, -0.012271846303085130f * (float)i);
        #pragma unroll
        for (int j = 0; j < 8; ++j) q[72*j] = x[j];
    }
    wsync();

    // ---- stage 2
    {
        v2f* q = p + 72*(i >> 3) + (i & 7);
        #pragma unroll
        for (int j = 0; j < 8; ++j) x[j] = q[9*j];
        bfly8(x);
        twiddle7(x, -0.098174770424681038f * (float)(i & 7));
        #pragma unroll
        for (int j = 0; j < 8; ++j) q[9*j] = x[j];
    }
    wsync();

    // ---- stage 3 + writeback (enables consecutive-ky regather)
    {
        v2f* q = p + 9*i;
        #pragma unroll
        for (int j = 0; j < 8; ++j) x[j] = q[j];
        bfly8(x);
        #pragma unroll
        for (int j = 0; j < 8; ++j) q[j] = x[j];
    }
    wsync();

    // ---- binning: lane h owns ky = 8h..8h+7 (storage fsw(c)+72j);
    // run-accumulate, LDS atomic per bin change; scale folded into flush.
    {
        const int h  = lane;
        const int kx = x0 + w;
        const bool valid = (kx <= 256);
        const float scale = (kx == 0 || kx == 256) ? 0.5f : 1.0f;
        const float dxf = (float)((kx - 256) * (kx - 256));
        float* bsw = bs + (w & 3) * 257;
        v2f* qb = p + fsw(8*(h & 7) + (h >> 3));
        float dyf = (float)(8*h - 256);

        float acc = 0.0f;
        int prevb = 1000;
        #pragma unroll
        for (int j = 0; j < 8; ++j) {
            const v2f v = qb[72*j];
            const float val = __log2f(fmaf(v.x, v.x, fmaf(v.y, v.y, EPSV)));
            const int b = (int)sqrtf(fmaf(dyf, dyf, dxf));
            dyf += 1.0f;
            if (b != prevb) {
                if (prevb < NBIN && valid) atomicAdd(&bsw[prevb], acc * scale);
                prevb = b; acc = val;
            } else {
                acc += val;
            }
        }
        if (prevb < NBIN && valid) atomicAdd(&bsw[prevb], acc * scale);
    }
    __syncthreads();

    if (t < NBIN) {
        float v = 0.0f;
        #pragma unroll
        for (int r = 0; r < 4; ++r) v += bs[r*257 + t];
        bins2[((size_t)blockIdx.x * NIMG + (img_base + li)) * NBIN + t] = 2.0f * v;
    }
}

// ---------------------------------------------------------------------------
// Reduce the 33 per-tile slices into bins[img][bin].
// ---------------------------------------------------------------------------
__global__ __launch_bounds__(256) void reduce_kernel(
    const float* __restrict__ bins2, float* __restrict__ bins)
{
    const int li = blockIdx.x;
    const int t  = threadIdx.x;
    float s = 0.0f;
    #pragma unroll
    for (int tile = 0; tile < NTILE; ++tile)
        s += bins2[((size_t)tile * NIMG + li) * NBIN + t];
    bins[(size_t)li * NBIN + t] = s;
}

// ---------------------------------------------------------------------------
__global__ __launch_bounds__(256) void counts_kernel(float* __restrict__ cnt)
{
    __shared__ float c[NBIN];
    const int t = threadIdx.x;
    c[t] = 0.0f;
    __syncthreads();

    const int base = blockIdx.x * 4096;
    #pragma unroll
    for (int i = 0; i < 16; ++i) {
        const int id = base + i * 256 + t;
        const int y = id >> 9, xx = id & 511;
        const int dy = y - 256, dx = xx - 256;
        const int b  = (int)sqrtf((float)(dy*dy + dx*dx));
        if (b < NBIN) atomicAdd(&c[b], 1.0f);
    }
    __syncthreads();
    if (c[t] != 0.0f) atomicAdd(&cnt[t], c[t]);
}

// ---------------------------------------------------------------------------
// Finalize: mean over (pair, bin) of |sum_p - sum_t| / cnt, times ln2
// (bins hold log2 sums; everything downstream is positively homogeneous).
// ---------------------------------------------------------------------------
__global__ __launch_bounds__(256) void finalize_kernel(
    const float* __restrict__ bins, const float* __restrict__ cnt,
    float* __restrict__ out)
{
    __shared__ float red[256];
    const int t = threadIdx.x;

    float acc = 0.0f;
    for (int id = t; id < NIMG_PER * NBIN; id += 256) {
        const int i = id >> 8;
        const int r = id & 255;
        const float d = fabsf(bins[(size_t)i * NBIN + r]
                            - bins[(size_t)(NIMG_PER + i) * NBIN + r]);
        acc += d / cnt[r];
    }
    red[t] = acc;
    __syncthreads();
    for (int w = 128; w > 0; w >>= 1) {
        if (t < w) red[t] += red[t + w];
        __syncthreads();
    }
    if (t == 0) out[0] = red[0] * (LN2F / (float)(NIMG_PER * NBIN));
}

// ---------------------------------------------------------------------------
extern "C" void kernel_launch(void* const* d_in, const int* in_sizes, int n_in,
                              void* d_out, int out_size, void* d_ws, size_t ws_size,
                              hipStream_t stream)
{
    const float* pred = (const float*)d_in[0];
    const float* targ = (const float*)d_in[1];
    float* out = (float*)d_out;

    char* ws = (char*)d_ws;
    float* cnt   = (float*)ws;                                  // 256
    float* bins  = cnt + NBIN;                                  // 192*256
    float* bins2 = bins + (size_t)NIMG * NBIN;                  // 33*192*256
    const size_t fixed_f = NBIN + (size_t)NIMG*NBIN + (size_t)NTILE*NIMG*NBIN;
    const size_t off = (fixed_f*sizeof(float) + 255) & ~(size_t)255;
    v2f* cbuf = (v2f*)(ws + off);

    const size_t per_img = (size_t)IMGC * sizeof(v2f);          // ~1.08 MiB
    size_t avail = (ws_size > off) ? (ws_size - off) : 0;
    int chunk = (int)(avail / per_img);
    if (chunk > NIMG) chunk = NIMG;
    if (chunk < 1) chunk = 1;

    hipMemsetAsync(cnt, 0, NBIN * sizeof(float), stream);
    counts_kernel<<<dim3(64), dim3(256), 0, stream>>>(cnt);

    for (int base = 0; base < NIMG; base += chunk) {
        const int n = (NIMG - base < chunk) ? (NIMG - base) : chunk;
        dim3 gA(HH / 16, n), gB(NTILE, n);
        rowfft_kernel<<<gA, dim3(512), 0, stream>>>(pred, targ, cbuf, base);
        colfft_kernel<<<gB, dim3(512), 0, stream>>>(cbuf, bins2, base);
    }

    reduce_kernel<<<dim3(NIMG), dim3(256), 0, stream>>>(bins2, bins);
    finalize_kernel<<<dim3(1), dim3(256), 0, stream>>>(bins, cnt, out);
}

// Round 11
// 212.908 us; speedup vs baseline: 1.2552x; 1.0598x over previous
//
#include <hip/hip_runtime.h>
#include <math.h>

#define HH 512
#define WW 512
#define IMG (HH*WW)
#define NIMG_PER 96   // B*C = 32*3
#define NIMG 192      // pred + targ
#define NBIN 256      // max_r
#define EPSV 1e-8f
#define LN2F 0.69314718055994530942f

#define CSTR 264               // padded column count (257 used + 7 zero pad)
#define IMGC (512*CSTR)        // h2 elems per image, row-major [y][kx]
#define NT16 17                // 16-column tiles (kx 0..271, valid <=256)
#define SLOT 575               // per-FFT LDS stride; fsw(511)=574<575

typedef float v2f  __attribute__((ext_vector_type(2)));  // packed-fp32 complex
typedef _Float16 h2f __attribute__((ext_vector_type(2)));

// octal-digit reversal of 9-bit index (3 radix-8 stages)
__device__ __forceinline__ int drev(int s) {
    return ((s & 7) << 6) | (s & 56) | (s >> 6);
}
// bank swizzle on element index
__device__ __forceinline__ int fsw(int a) { return a + (a >> 3); }

__device__ __forceinline__ v2f cmul(v2f a, v2f b) {
    return (v2f){a.x, a.x} * b + (v2f){a.y, a.y} * (v2f){-b.y, b.x};
}
__device__ __forceinline__ v2f cni(v2f a) { return (v2f){a.y, -a.x}; }  // * -i

// f16<->f32 complex pack/unpack (storage f16, math f32)
__device__ __forceinline__ v2f h2tof(unsigned int u) {
    h2f h = __builtin_bit_cast(h2f, u);
    return (v2f){(float)h.x, (float)h.y};
}
__device__ __forceinline__ unsigned int ftoh2(v2f v) {
    return __builtin_bit_cast(unsigned int, __builtin_amdgcn_cvt_pkrtz(v.x, v.y));
}

// intra-wave "barrier": LDS is in-order per wave; stop compiler reordering
__device__ __forceinline__ void wsync() {
    asm volatile("" ::: "memory");
    __builtin_amdgcn_wave_barrier();
    asm volatile("" ::: "memory");
}

// radix-8 DIF butterfly, negative exponent — packed-2 fp32 ops
__device__ __forceinline__ void bfly8(v2f x[8]) {
    const float R = 0.70710678118654752440f;
    v2f t0=x[0]+x[4], t4=x[0]-x[4];
    v2f t1=x[1]+x[5], t5=x[1]-x[5];
    v2f t2=x[2]+x[6], t6=x[2]-x[6];
    v2f t3=x[3]+x[7], t7=x[3]-x[7];
    v2f u0=t0+t2, u2=t0-t2;
    v2f u1=t1+t3, u3=t1-t3;
    x[0]=u0+u1; x[4]=u0-u1;
    { v2f n3 = cni(u3); x[2]=u2+n3; x[6]=u2-n3; }
    v2f s1 = (v2f){R, R} * ((v2f){t5.x, t5.y} + (v2f){t5.y, -t5.x});
    v2f s2 = cni(t6);
    v2f s3 = (v2f){R, R} * ((v2f){t7.y, -t7.x} - (v2f){t7.x, t7.y});
    v2f v0=t4+s2, v2_=t4-s2;
    v2f v1=s1+s3, v3=s1-s3;
    x[1]=v0+v1; x[5]=v0-v1;
    { v2f m3 = cni(v3); x[3]=v2_+m3; x[7]=v2_-m3; }
}

// x[j] *= w^j, w = exp(i*ang)
__device__ __forceinline__ void twiddle7(v2f* x, float ang) {
    const float sn = __sinf(ang), cs = __cosf(ang);
    const v2f w1 = (v2f){cs, sn};
    const v2f w2 = cmul(w1, w1);
    const v2f w3 = cmul(w2, w1);
    const v2f w4 = cmul(w2, w2);
    const v2f w5 = cmul(w2, w3);
    const v2f w6 = cmul(w3, w3);
    const v2f w7 = cmul(w3, w4);
    x[1]=cmul(x[1],w1); x[2]=cmul(x[2],w2); x[3]=cmul(x[3],w3);
    x[4]=cmul(x[4],w4); x[5]=cmul(x[5],w5); x[6]=cmul(x[6],w6);
    x[7]=cmul(x[7],w7);
}

// ---------------------------------------------------------------------------
// Pass A: 512-thr block = 8 waves = 8 row-pairs (16 image rows), ZERO block
// barriers. Stage-1 direct from global; f32 LDS; Hermitian unpack ->
// coalesced f16 [y][kx] stores (4B per column).
// ---------------------------------------------------------------------------
__global__ __launch_bounds__(512) void rowfft_kernel(
    const float* __restrict__ pred, const float* __restrict__ targ,
    unsigned int* __restrict__ out, int img_base)
{
    __shared__ v2f sd[8*SLOT];
    const int t    = threadIdx.x;
    const int lane = t & 63;
    const int w    = t >> 6;

    const int pb = blockIdx.x;          // rows pb*16 .. pb*16+15
    const int li = blockIdx.y;
    const int g  = img_base + li;
    const float* img = (g < NIMG_PER) ? (pred + (size_t)g * IMG)
                                      : (targ + (size_t)(g - NIMG_PER) * IMG);
    const float* rowA = img + (size_t)(pb*16 + 2*w) * WW + lane;
    const float* rowB = rowA + WW;

    v2f* p = sd + w * SLOT;
    v2f x[8];
    const int i = lane;

    // ---- stage 1: global->reg (coalesced, immediate offsets), bfly, twiddle
    #pragma unroll
    for (int j = 0; j < 8; ++j)
        x[j] = (v2f){rowA[64*j], rowB[64*j]};
    bfly8(x);
    twiddle7(x, -0.012271846303085130f * (float)i);       // -2pi/512 * i
    {
        v2f* q = p + fsw(i);
        #pragma unroll
        for (int j = 0; j < 8; ++j) q[72*j] = x[j];
    }
    wsync();

    // ---- stage 2
    {
        v2f* q = p + 72*(i >> 3) + (i & 7);
        #pragma unroll
        for (int j = 0; j < 8; ++j) x[j] = q[9*j];
        bfly8(x);
        twiddle7(x, -0.098174770424681038f * (float)(i & 7));   // -2pi/64 * i2
        #pragma unroll
        for (int j = 0; j < 8; ++j) q[9*j] = x[j];
    }
    wsync();

    // ---- stage 3: contiguous
    {
        v2f* q = p + 9*i;
        #pragma unroll
        for (int j = 0; j < 8; ++j) x[j] = q[j];
        bfly8(x);
        #pragma unroll
        for (int j = 0; j < 8; ++j) q[j] = x[j];
    }
    wsync();

    // ---- Hermitian unpack, consecutive k per lane -> coalesced f16 stores.
    unsigned int* dstA = out + (size_t)li * IMGC + (size_t)(pb*16 + 2*w) * CSTR;
    unsigned int* dstB = dstA + CSTR;
    #pragma unroll
    for (int it = 0; it < 5; ++it) {
        const int k = it*64 + lane;
        if (k <= 256) {
            const v2f P = p[fsw(drev(k))];
            const v2f Q = p[fsw(drev((512 - k) & 511))];
            const v2f Fa = (v2f){0.5f, 0.5f} * (P + (v2f){Q.x, -Q.y});
            const v2f Fb = (v2f){0.5f, 0.5f} * ((v2f){P.y, -P.x} + (v2f){Q.y, Q.x});
            dstA[k] = ftoh2(Fa);
            dstB[k] = ftoh2(Fb);
        } else if (k < CSTR) {          // zero the 7 pad columns (h2 zero = 0)
            dstA[k] = 0u;
            dstB[k] = 0u;
        }
    }
}

// ---------------------------------------------------------------------------
// Pass B: 512-thr block = 8 waves, 16-column tile, TWO columns per wave
// (independent dependency chains interleaved at every LDS stall; shared
// twiddles). f16 LDS storage keeps footprint at 3 blocks/CU with 24 waves ->
// 48 concurrent chains/CU. Two block barriers total.
// ---------------------------------------------------------------------------
__global__ __launch_bounds__(512) void colfft_kernel(
    const unsigned int* __restrict__ in, float* __restrict__ bins2, int img_base)
{
    __shared__ unsigned int sd[16*SLOT];   // f16-complex per element
    __shared__ float bs[4*257];            // replica w&3 (waves w, w+4 share)
    const int t    = threadIdx.x;
    const int lane = t & 63;
    const int w    = t >> 6;

    for (int id = t; id < 4*257; id += 512) bs[id] = 0.0f;

    const int li = blockIdx.y;
    const int x0 = blockIdx.x * 16;
    // staging: lane loads uint4 = 4 adjacent f16 columns at one row (64B/row
    // with the 4 groups -> full cachelines). Clamp keeps the last tile's
    // reads in-bounds (clamped cols land in zero padding; invalid anyway).
    {
        const int y0 = t >> 2;             // 0..127
        const int c  = t & 3;              // column quad 0..3
        int cb = x0 + 4*c;
        if (cb > CSTR - 4) cb = CSTR - 4;
        const uint4* gsrc = (const uint4*)(in + (size_t)li * IMGC
                                              + (size_t)y0 * CSTR + cb);
        unsigned int* d0 = sd + (4*c + 0)*SLOT + fsw(y0);
        unsigned int* d1 = d0 + SLOT;
        unsigned int* d2 = d1 + SLOT;
        unsigned int* d3 = d2 + SLOT;
        #pragma unroll
        for (int it = 0; it < 4; ++it) {   // y = y0+128it; fsw -> +144it
            const uint4 v = gsrc[(size_t)it * 128 * (CSTR/4)];
            d0[144*it] = v.x; d1[144*it] = v.y;
            d2[144*it] = v.z; d3[144*it] = v.w;
        }
    }
    __syncthreads();

    // wave w owns columns x0+2w, x0+2w+1 end-to-end
    unsigned int* pA = sd + (2*w)     * SLOT;
    unsigned int* pB = sd + (2*w + 1) * SLOT;
    v2f a[8], b[8];
    const int i = lane;

    // ---- stage 1
    {
        unsigned int* qA = pA + fsw(i);
        unsigned int* qB = pB + fsw(i);
        #pragma unroll
        for (int j = 0; j < 8; ++j) { a[j] = h2tof(qA[72*j]); b[j] = h2tof(qB[72*j]); }
        bfly8(a); bfly8(b);
        const float ang = -0.012271846303085130f * (float)i;
        const float sn = __sinf(ang), cs = __cosf(ang);
        const v2f w1 = (v2f){cs, sn};
        const v2f w2 = cmul(w1,w1), w3 = cmul(w2,w1), w4 = cmul(w2,w2);
        const v2f w5 = cmul(w2,w3), w6 = cmul(w3,w3), w7 = cmul(w3,w4);
        a[1]=cmul(a[1],w1); b[1]=cmul(b[1],w1);
        a[2]=cmul(a[2],w2); b[2]=cmul(b[2],w2);
        a[3]=cmul(a[3],w3); b[3]=cmul(b[3],w3);
        a[4]=cmul(a[4],w4); b[4]=cmul(b[4],w4);
        a[5]=cmul(a[5],w5); b[5]=cmul(b[5],w5);
        a[6]=cmul(a[6],w6); b[6]=cmul(b[6],w6);
        a[7]=cmul(a[7],w7); b[7]=cmul(b[7],w7);
        #pragma unroll
        for (int j = 0; j < 8; ++j) { qA[72*j] = ftoh2(a[j]); qB[72*j] = ftoh2(b[j]); }
    }
    wsync();

    // ---- stage 2
    {
        const int off = 72*(i >> 3) + (i & 7);
        unsigned int* qA = pA + off;
        unsigned int* qB = pB + off;
        #pragma unroll
        for (int j = 0; j < 8; ++j) { a[j] = h2tof(qA[9*j]); b[j] = h2tof(qB[9*j]); }
        bfly8(a); bfly8(b);
        const float ang = -0.098174770424681038f * (float)(i & 7);
        const float sn = __sinf(ang), cs = __cosf(ang);
        const v2f w1 = (v2f){cs, sn};
        const v2f w2 = cmul(w1,w1), w3 = cmul(w2,w1), w4 = cmul(w2,w2);
        const v2f w5 = cmul(w2,w3), w6 = cmul(w3,w3), w7 = cmul(w3,w4);
        a[1]=cmul(a[1],w1); b[1]=cmul(b[1],w1);
        a[2]=cmul(a[2],w2); b[2]=cmul(b[2],w2);
        a[3]=cmul(a[3],w3); b[3]=cmul(b[3],w3);
        a[4]=cmul(a[4],w4); b[4]=cmul(b[4],w4);
        a[5]=cmul(a[5],w5); b[5]=cmul(b[5],w5);
        a[6]=cmul(a[6],w6); b[6]=cmul(b[6],w6);
        a[7]=cmul(a[7],w7); b[7]=cmul(b[7],w7);
        #pragma unroll
        for (int j = 0; j < 8; ++j) { qA[9*j] = ftoh2(a[j]); qB[9*j] = ftoh2(b[j]); }
    }
    wsync();

    // ---- stage 3 + writeback (enables consecutive-ky regather)
    {
        unsigned int* qA = pA + 9*i;
        unsigned int* qB = pB + 9*i;
        #pragma unroll
        for (int j = 0; j < 8; ++j) { a[j] = h2tof(qA[j]); b[j] = h2tof(qB[j]); }
        bfly8(a); bfly8(b);
        #pragma unroll
        for (int j = 0; j < 8; ++j) { qA[j] = ftoh2(a[j]); qB[j] = ftoh2(b[j]); }
    }
    wsync();

    // ---- binning: lane h owns ky = 8h..8h+7 of both columns; two
    // independent run-accumulators; LDS atomic per bin change.
    {
        const int h   = lane;
        const int kxA = x0 + 2*w;
        const int kxB = kxA + 1;
        const bool vA = (kxA <= 256), vB = (kxB <= 256);
        const float sA = (kxA == 0 || kxA == 256) ? 0.5f : 1.0f;
        const float sB = (kxB == 256) ? 0.5f : 1.0f;
        const float dxA = (float)((kxA - 256) * (kxA - 256));
        const float dxB = (float)((kxB - 256) * (kxB - 256));
        float* bsw = bs + (w & 3) * 257;
        const int off = fsw(8*(h & 7) + (h >> 3));
        unsigned int* qA = pA + off;
        unsigned int* qB = pB + off;
        float dyf = (float)(8*h - 256);

        float accA = 0.0f, accB = 0.0f;
        int pbA = 1000, pbB = 1000;
        #pragma unroll
        for (int j = 0; j < 8; ++j) {
            const v2f va = h2tof(qA[72*j]);
            const v2f vb = h2tof(qB[72*j]);
            const float la = __log2f(fmaf(va.x, va.x, fmaf(va.y, va.y, EPSV)));
            const float lb = __log2f(fmaf(vb.x, vb.x, fmaf(vb.y, vb.y, EPSV)));
            const int bA = (int)sqrtf(fmaf(dyf, dyf, dxA));
            const int bB = (int)sqrtf(fmaf(dyf, dyf, dxB));
            dyf += 1.0f;
            if (bA != pbA) {
                if (pbA < NBIN && vA) atomicAdd(&bsw[pbA], accA * sA);
                pbA = bA; accA = la;
            } else accA += la;
            if (bB != pbB) {
                if (pbB < NBIN && vB) atomicAdd(&bsw[pbB], accB * sB);
                pbB = bB; accB = lb;
            } else accB += lb;
        }
        if (pbA < NBIN && vA) atomicAdd(&bsw[pbA], accA * sA);
        if (pbB < NBIN && vB) atomicAdd(&bsw[pbB], accB * sB);
    }
    __syncthreads();

    if (t < NBIN) {
        float v = 0.0f;
        #pragma unroll
        for (int r = 0; r < 4; ++r) v += bs[r*257 + t];
        bins2[((size_t)blockIdx.x * NIMG + (img_base + li)) * NBIN + t] = 2.0f * v;
    }
}

// ---------------------------------------------------------------------------
// Reduce the 17 per-tile slices into bins[img][bin].
// ---------------------------------------------------------------------------
__global__ __launch_bounds__(256) void reduce_kernel(
    const float* __restrict__ bins2, float* __restrict__ bins)
{
    const int li = blockIdx.x;
    const int t  = threadIdx.x;
    float s = 0.0f;
    #pragma unroll
    for (int tile = 0; tile < NT16; ++tile)
        s += bins2[((size_t)tile * NIMG + li) * NBIN + t];
    bins[(size_t)li * NBIN + t] = s;
}

// ---------------------------------------------------------------------------
__global__ __launch_bounds__(256) void counts_kernel(float* __restrict__ cnt)
{
    __shared__ float c[NBIN];
    const int t = threadIdx.x;
    c[t] = 0.0f;
    __syncthreads();

    const int base = blockIdx.x * 4096;
    #pragma unroll
    for (int i = 0; i < 16; ++i) {
        const int id = base + i * 256 + t;
        const int y = id >> 9, xx = id & 511;
        const int dy = y - 256, dx = xx - 256;
        const int b  = (int)sqrtf((float)(dy*dy + dx*dx));
        if (b < NBIN) atomicAdd(&c[b], 1.0f);
    }
    __syncthreads();
    if (c[t] != 0.0f) atomicAdd(&cnt[t], c[t]);
}

// ---------------------------------------------------------------------------
// Finalize: mean over (pair, bin) of |sum_p - sum_t| / cnt, times ln2
// (bins hold log2 sums; everything downstream is positively homogeneous).
// ---------------------------------------------------------------------------
__global__ __launch_bounds__(256) void finalize_kernel(
    const float* __restrict__ bins, const float* __restrict__ cnt,
    float* __restrict__ out)
{
    __shared__ float red[256];
    const int t = threadIdx.x;

    float acc = 0.0f;
    for (int id = t; id < NIMG_PER * NBIN; id += 256) {
        const int i = id >> 8;
        const int r = id & 255;
        const float d = fabsf(bins[(size_t)i * NBIN + r]
                            - bins[(size_t)(NIMG_PER + i) * NBIN + r]);
        acc += d / cnt[r];
    }
    red[t] = acc;
    __syncthreads();
    for (int w = 128; w > 0; w >>= 1) {
        if (t < w) red[t] += red[t + w];
        __syncthreads();
    }
    if (t == 0) out[0] = red[0] * (LN2F / (float)(NIMG_PER * NBIN));
}

// ---------------------------------------------------------------------------
extern "C" void kernel_launch(void* const* d_in, const int* in_sizes, int n_in,
                              void* d_out, int out_size, void* d_ws, size_t ws_size,
                              hipStream_t stream)
{
    const float* pred = (const float*)d_in[0];
    const float* targ = (const float*)d_in[1];
    float* out = (float*)d_out;

    char* ws = (char*)d_ws;
    float* cnt   = (float*)ws;                                  // 256
    float* bins  = cnt + NBIN;                                  // 192*256
    float* bins2 = bins + (size_t)NIMG * NBIN;                  // 17*192*256
    const size_t fixed_f = NBIN + (size_t)NIMG*NBIN + (size_t)NT16*NIMG*NBIN;
    const size_t off = (fixed_f*sizeof(float) + 255) & ~(size_t)255;
    unsigned int* cbuf = (unsigned int*)(ws + off);             // f16 complex

    const size_t per_img = (size_t)IMGC * sizeof(unsigned int); // ~528 KiB
    size_t avail = (ws_size > off) ? (ws_size - off) : 0;
    int chunk = (int)(avail / per_img);
    if (chunk > NIMG) chunk = NIMG;
    if (chunk < 1) chunk = 1;

    hipMemsetAsync(cnt, 0, NBIN * sizeof(float), stream);
    counts_kernel<<<dim3(64), dim3(256), 0, stream>>>(cnt);

    for (int base = 0; base < NIMG; base += chunk) {
        const int n = (NIMG - base < chunk) ? (NIMG - base) : chunk;
        dim3 gA(HH / 16, n), gB(NT16, n);
        rowfft_kernel<<<gA, dim3(512), 0, stream>>>(pred, targ, cbuf, base);
        colfft_kernel<<<gB, dim3(512), 0, stream>>>(cbuf, bins2, base);
    }

    reduce_kernel<<<dim3(NIMG), dim3(256), 0, stream>>>(bins2, bins);
    finalize_kernel<<<dim3(1), dim3(256), 0, stream>>>(bins, cnt, out);
}